// Round 1
// baseline (1127.145 us; speedup 1.0000x reference)
//
#include <hip/hip_runtime.h>
#include <hip/hip_bf16.h>

// FCCaps capsule routing, MI355X.
// x[32,1024,128] f32, w1[1024,20,64,128] f32.
// u_hat[b,n,c,d] = sum_i w1[n,c,d,i]*x[b,n,i]; 3 routing iterations;
// out = poses[32,20,64,1] ++ activations[32,20,1].
//
// R2: (1) pass_uhat double-buffers the W tile (one 8KB tile always in
//     flight per wave); (2) pass_route 2x more blocks (4 n/wave), k-loop
//     fully unrolled with per-parity LDS buffers so the 4 chains are
//     independent, block reduce via LDS atomics. Numerics bit-identical
//     to R1 (same rounding helpers, same MFMA order per tile).

#define NCLS 20
#define NIN  1024
#define CIN  128
#define DOUT 64
#define BATCH 32
#define MCD  1280   // NCLS*DOUT flattened

typedef __attribute__((ext_vector_type(8))) short bf16x8;
typedef __attribute__((ext_vector_type(4))) float f32x4;

__device__ __forceinline__ float b2f(unsigned short u) {
    union { unsigned int i; float f; } v; v.i = ((unsigned int)u) << 16; return v.f;
}
__device__ __forceinline__ unsigned short f2b_rne(float f) {
    union { float f; unsigned int i; } v; v.f = f;
    unsigned int x = v.i;
    return (unsigned short)((x + 0x7fffu + ((x >> 16) & 1u)) >> 16);
}
// split 8 fp32 into hi-bf16 + lo-bf16 (residual) fragments
__device__ __forceinline__ void cvt_hilo(const float* v, bf16x8& h, bf16x8& l) {
#pragma unroll
    for (int j = 0; j < 8; ++j) {
        unsigned short hb = f2b_rne(v[j]);
        h[j] = (short)hb;
        l[j] = (short)f2b_rne(v[j] - b2f(hb));
    }
}

// ---------------------------------------------------------------------------
// Pass A (MFMA): per n, D[b=32, cd=1280] = x[32,128] * w1[n]^T[128,1280].
// grid = 1024 n x 2 halves; 256 thr = 4 waves; wave handles 10 nt (16-col
// tiles). Double-buffered W loads: tile nt+1 is issued before tile nt's
// cvt+MFMA, so each wave always has an 8KB tile in flight (HBM latency
// hidden instead of exposed once per nt).
// D layout (HW-verified): row(b) = (lane>>4)*4+reg, col(cd) = lane&15.
// ---------------------------------------------------------------------------
__global__ __launch_bounds__(256) void pass_uhat(
    const float* __restrict__ x, const float* __restrict__ W,
    unsigned short* __restrict__ uhat)
{
    const int n    = blockIdx.x >> 1;
    const int half = blockIdx.x & 1;
    const int t    = threadIdx.x;
    const int wave = t >> 6;
    const int lane = t & 63;
    const int lm   = lane & 15;
    const int lq   = lane >> 4;

    // ---- A-fragments (x) in registers, hi/lo split
    bf16x8 xh[2][4], xl[2][4];
#pragma unroll
    for (int mt = 0; mt < 2; ++mt) {
        const float* xrow = x + ((size_t)(mt * 16 + lm) * NIN + n) * CIN + lq * 8;
#pragma unroll
        for (int ks = 0; ks < 4; ++ks) {
            float v[8];
            *reinterpret_cast<float4*>(&v[0]) = *reinterpret_cast<const float4*>(xrow + ks * 32);
            *reinterpret_cast<float4*>(&v[4]) = *reinterpret_cast<const float4*>(xrow + ks * 32 + 4);
            cvt_hilo(v, xh[mt][ks], xl[mt][ks]);
        }
    }

    const int nt0 = half * 40 + wave * 10;
    const float* wbase = W + (size_t)n * MCD * CIN;

    float4 wA[8], wB[8];   // double buffer, statically indexed only

#define ISSUE(NTC, BUF) do {                                                   \
    const float* wp_ = wbase + (size_t)((nt0 + (NTC)) * 16 + lm) * CIN + lq*8; \
    _Pragma("unroll")                                                          \
    for (int ks = 0; ks < 4; ++ks) {                                           \
        BUF[2*ks]   = *reinterpret_cast<const float4*>(wp_ + ks * 32);         \
        BUF[2*ks+1] = *reinterpret_cast<const float4*>(wp_ + ks * 32 + 4);     \
    } } while (0)

#define COMPUTE(NTC, BUF) do {                                                 \
    f32x4 acc0 = {0.f,0.f,0.f,0.f};                                            \
    f32x4 acc1 = {0.f,0.f,0.f,0.f};                                            \
    _Pragma("unroll")                                                          \
    for (int ks = 0; ks < 4; ++ks) {                                           \
        float v_[8];                                                           \
        *reinterpret_cast<float4*>(&v_[0]) = BUF[2*ks];                        \
        *reinterpret_cast<float4*>(&v_[4]) = BUF[2*ks+1];                      \
        bf16x8 wh_, wl_;                                                       \
        cvt_hilo(v_, wh_, wl_);                                                \
        acc0 = __builtin_amdgcn_mfma_f32_16x16x32_bf16(xh[0][ks], wh_, acc0, 0,0,0); \
        acc1 = __builtin_amdgcn_mfma_f32_16x16x32_bf16(xh[1][ks], wh_, acc1, 0,0,0); \
        acc0 = __builtin_amdgcn_mfma_f32_16x16x32_bf16(xh[0][ks], wl_, acc0, 0,0,0); \
        acc1 = __builtin_amdgcn_mfma_f32_16x16x32_bf16(xh[1][ks], wl_, acc1, 0,0,0); \
        acc0 = __builtin_amdgcn_mfma_f32_16x16x32_bf16(xl[0][ks], wh_, acc0, 0,0,0); \
        acc1 = __builtin_amdgcn_mfma_f32_16x16x32_bf16(xl[1][ks], wh_, acc1, 0,0,0); \
    }                                                                          \
    const int cd_ = (nt0 + (NTC)) * 16 + lm;                                   \
    _Pragma("unroll")                                                          \
    for (int mt = 0; mt < 2; ++mt) {                                           \
        f32x4 a_ = mt ? acc1 : acc0;                                           \
        _Pragma("unroll")                                                      \
        for (int r = 0; r < 4; ++r) {                                          \
            int br_ = mt * 16 + lq * 4 + r;                                    \
            uhat[((size_t)br_ * NIN + n) * MCD + cd_] = f2b_rne(a_[r]);        \
        } } } while (0)

    ISSUE(0, wA);
#pragma unroll
    for (int p = 0; p < 5; ++p) {
        ISSUE(2*p + 1, wB);          // prefetch odd tile
        COMPUTE(2*p, wA);            // compute even tile
        if (p < 4) ISSUE(2*p + 2, wA);  // prefetch next even tile
        COMPUTE(2*p + 1, wB);        // compute odd tile
    }
#undef ISSUE
#undef COMPUTE
}

// ---------------------------------------------------------------------------
// Pass S0: s0_raw[b,cd] = sum_n u_hat[b,n,cd]. grid = 32 b x 16 n-chunks,
// block = 320 threads: thread t owns ushort4 #t of each 2560-B row (perfectly
// coalesced streaming), accumulates over 64 n, 4 atomics at the end.
// ---------------------------------------------------------------------------
__global__ __launch_bounds__(320) void pass_s0(
    const unsigned short* __restrict__ uhat, float* __restrict__ s0raw)
{
    const int b     = blockIdx.x >> 4;
    const int chunk = blockIdx.x & 15;
    const int t     = threadIdx.x;          // 0..319

    const ushort4* base = reinterpret_cast<const ushort4*>(
        uhat + ((size_t)b * NIN + chunk * 64) * MCD) + t;
    float a0 = 0.f, a1 = 0.f, a2 = 0.f, a3 = 0.f;
#pragma unroll 4
    for (int k = 0; k < 64; ++k) {
        ushort4 u = base[(size_t)k * 320];
        a0 += b2f(u.x); a1 += b2f(u.y); a2 += b2f(u.z); a3 += b2f(u.w);
    }
    float* dst = s0raw + (size_t)b * MCD + t * 4;
    atomicAdd(dst + 0, a0);
    atomicAdd(dst + 1, a1);
    atomicAdd(dst + 2, a2);
    atomicAdd(dst + 3, a3);
}

// ---------------------------------------------------------------------------
// Pass V: v = squash(s_raw * inv). grid = 640 (b*20+c), 64 thr (lane = d).
// ---------------------------------------------------------------------------
__global__ void pass_v(const float* __restrict__ sraw, const float* __restrict__ Zc,
                       float invz_uniform, float* __restrict__ vbuf,
                       float* __restrict__ vn2,
                       float* __restrict__ out_poses, float* __restrict__ out_act)
{
    const int bc   = blockIdx.x;
    const int lane = threadIdx.x;
    const int idx  = bc * 64 + lane;
    float inv = (Zc != nullptr) ? (1.0f / Zc[bc]) : invz_uniform;
    float s  = sraw[idx] * inv;
    float s2 = s * s;
#pragma unroll
    for (int o = 32; o >= 1; o >>= 1) s2 += __shfl_xor(s2, o, 64);
    float norm  = sqrtf(s2);
    float scale = norm / (0.5f + s2);
    float v = scale * s;
    vbuf[idx] = v;
    float vn = scale * scale * s2;             // |v|^2
    if (lane == 0) vn2[bc] = vn;
    if (out_poses != nullptr) {
        out_poses[idx] = v;
        if (lane == 0) out_act[bc] = sqrtf(vn);
    }
}

// ---------------------------------------------------------------------------
// Pass ROUTE (one routing iteration, fused). grid = 32b x 64 n-chunks;
// 256 thr; 4 n per wave (k fully unrolled; per-parity LDS buffers so the
// k-chains are independent -> ILP instead of one long serial chain).
// Cross-wave s' reduce via LDS atomics into one shared buffer.
// ---------------------------------------------------------------------------
__global__ __launch_bounds__(256) void pass_route(
    const unsigned short* __restrict__ uhat, const float* __restrict__ vbuf,
    const float* __restrict__ vn2, float* __restrict__ bij,
    float* __restrict__ snext, float* __restrict__ Znext)
{
    const int b     = blockIdx.x >> 6;
    const int chunk = blockIdx.x & 63;
    const int t     = threadIdx.x;
    const int wave  = t >> 6;
    const int lane  = t & 63;

    __shared__ float Vs[20 * 65];          // v[c][d], stride 65
    __shared__ float sacc_sh[20 * 64];     // block-level s' accumulator
    __shared__ float zsh[20];
    __shared__ float qrow[4][2][20], prow[4][2][20], scrow[4][2][20];

    for (int idx = t; idx < 20 * 65; idx += 256) {
        int cc = idx / 65, dd = idx % 65;
        Vs[idx] = (dd < 64) ? vbuf[(size_t)b * MCD + cc * 64 + dd] : 0.f;
    }
    for (int idx = t; idx < 20 * 64; idx += 256) sacc_sh[idx] = 0.f;
    if (t < 20) zsh[t] = 0.f;
    __syncthreads();

    const int cmy   = lane >> 4;
    const int dbase = (lane & 15) * 4;
    const float vnb = vn2[b * NCLS + (lane < 20 ? lane : 0)];

    float sacc[5][4];
#pragma unroll
    for (int tt = 0; tt < 5; ++tt)
#pragma unroll
        for (int j = 0; j < 4; ++j) sacc[tt][j] = 0.f;
    float zacc = 0.f;

    const int n0 = chunk * 16 + wave * 4;
#pragma unroll
    for (int k = 0; k < 4; ++k) {
        const int n   = n0 + k;
        const int par = k & 1;
        const ushort4* up = reinterpret_cast<const ushort4*>(
            uhat + ((size_t)b * NIN + n) * MCD);

        float uf[5][4];
#pragma unroll
        for (int tt = 0; tt < 5; ++tt) {
            ushort4 uq = up[tt * 64 + lane];
            uf[tt][0] = b2f(uq.x); uf[tt][1] = b2f(uq.y);
            uf[tt][2] = b2f(uq.z); uf[tt][3] = b2f(uq.w);
        }
#pragma unroll
        for (int tt = 0; tt < 5; ++tt) {
            int cc = tt * 4 + cmy;
            float q = 0.f, p = 0.f;
#pragma unroll
            for (int j = 0; j < 4; ++j) {
                float u = uf[tt][j];
                q = fmaf(u, u, q);
                p = fmaf(u, Vs[cc * 65 + dbase + j], p);
            }
#pragma unroll
            for (int o = 8; o >= 1; o >>= 1) {
                q += __shfl_xor(q, o, 16);
                p += __shfl_xor(p, o, 16);
            }
            if ((lane & 15) == 0) { qrow[wave][par][cc] = q; prow[wave][par][cc] = p; }
        }
        // wave-local: LDS write->read ordered by lgkmcnt, no block barrier
        {
            float val = -1e30f;
            if (lane < 20) {
                float q  = qrow[wave][par][lane];
                float p  = prow[wave][par][lane];
                float qs = sqrtf(q);
                float su = qs / (0.5f + q);
                float dd = 1.f - su * su * q + 2.f * su * p - vnb;
                size_t bidx = ((size_t)b * NIN + n) * NCLS + lane;
                float bnew = bij[bidx] + dd;
                bij[bidx] = bnew;
                val = bnew;
            }
            float mx = val;
#pragma unroll
            for (int o = 16; o >= 1; o >>= 1) mx = fmaxf(mx, __shfl_xor(mx, o, 32));
            float e = (lane < 20) ? __expf(val - mx) : 0.f;
            float se = e;
#pragma unroll
            for (int o = 16; o >= 1; o >>= 1) se += __shfl_xor(se, o, 32);
            if (lane < 20) {
                float sc = e / se;
                scrow[wave][par][lane] = sc;
                zacc += sc;
            }
        }
#pragma unroll
        for (int tt = 0; tt < 5; ++tt) {
            float sc = scrow[wave][par][tt * 4 + cmy];
#pragma unroll
            for (int j = 0; j < 4; ++j)
                sacc[tt][j] = fmaf(sc, uf[tt][j], sacc[tt][j]);
        }
    }

    // cross-wave reduce: LDS atomics (each lane owns 20 disjoint-per-wave
    // contributions; 4 waves collide per address -> ds_add handles it)
#pragma unroll
    for (int tt = 0; tt < 5; ++tt) {
        int cc = tt * 4 + cmy;
#pragma unroll
        for (int j = 0; j < 4; ++j)
            atomicAdd(&sacc_sh[cc * 64 + dbase + j], sacc[tt][j]);
    }
    if (lane < 20) atomicAdd(&zsh[lane], zacc);
    __syncthreads();

    for (int idx = t; idx < NCLS * DOUT; idx += 256) {
        int cc = idx >> 6, dd = idx & 63;
        atomicAdd(&snext[(size_t)(b * NCLS + cc) * DOUT + dd], sacc_sh[idx]);
    }
    if (t < 20) atomicAdd(&Znext[b * NCLS + t], zsh[t]);
}

// ---------------------------------------------------------------------------
extern "C" void kernel_launch(void* const* d_in, const int* in_sizes, int n_in,
                              void* d_out, int out_size, void* d_ws, size_t ws_size,
                              hipStream_t stream)
{
    (void)in_sizes; (void)n_in; (void)out_size; (void)ws_size;
    const float* x  = (const float*)d_in[0];
    const float* w1 = (const float*)d_in[1];
    float* out = (float*)d_out;

    char* ws = (char*)d_ws;
    unsigned short* uhat = (unsigned short*)ws;                 // 32*1024*1280 * 2B
    size_t off = (size_t)BATCH * NIN * MCD * 2;                 // 83,886,080
    float* s0   = (float*)(ws + off); off += (size_t)BATCH * MCD * 4;
    float* s1   = (float*)(ws + off); off += (size_t)BATCH * MCD * 4;
    float* s2   = (float*)(ws + off); off += (size_t)BATCH * MCD * 4;
    float* Z1   = (float*)(ws + off); off += (size_t)BATCH * NCLS * 4;
    float* Z2   = (float*)(ws + off); off += (size_t)BATCH * NCLS * 4;
    float* bij  = (float*)(ws + off); off += (size_t)BATCH * NIN * NCLS * 4;
    float* vbuf = (float*)(ws + off); off += (size_t)BATCH * MCD * 4;
    float* vn2  = (float*)(ws + off); off += (size_t)BATCH * NCLS * 4;

    // zero accumulators + b_ij (contiguous region: s0..bij)
    size_t zbytes = (size_t)3 * BATCH * MCD * 4 + 2 * BATCH * NCLS * 4
                  + (size_t)BATCH * NIN * NCLS * 4;
    hipMemsetAsync(s0, 0, zbytes, stream);

    pass_uhat <<<NIN * 2, 256, 0, stream>>>(x, w1, uhat);
    pass_s0   <<<BATCH * 16, 320, 0, stream>>>(uhat, s0);
    pass_v    <<<BATCH * NCLS, 64, 0, stream>>>(s0, nullptr, 1.0f / 1024.0f,
                                                vbuf, vn2, nullptr, nullptr);
    pass_route<<<BATCH * 64, 256, 0, stream>>>(uhat, vbuf, vn2, bij, s1, Z1);
    pass_v    <<<BATCH * NCLS, 64, 0, stream>>>(s1, Z1, 0.f, vbuf, vn2, nullptr, nullptr);
    pass_route<<<BATCH * 64, 256, 0, stream>>>(uhat, vbuf, vn2, bij, s2, Z2);
    pass_v    <<<BATCH * NCLS, 64, 0, stream>>>(s2, Z2, 0.f, vbuf, vn2,
                                                out, out + BATCH * MCD);
}